// Round 1
// baseline (14509.508 us; speedup 1.0000x reference)
//
#include <hip/hip_runtime.h>

#define B_ 256
#define T_ 512
#define I_ 128
#define H_ 256
#define C_ 1000

#define LDSTR 132   // padded LDS row stride in floats (128 + 4), 16B-aligned
#define RSTR  20    // reduction row stride in floats (16 + 4), 16B-aligned

__device__ __forceinline__ float fsig(float x) { return 1.0f / (1.0f + __expf(-x)); }
__device__ __forceinline__ float ftanh(float x) { return 2.0f / (1.0f + __expf(-2.0f * x)) - 1.0f; }

// Per-step kernel: wgs [0,256) do layer-0 at t=s; wgs [256,512) do layer-1 at t=s-1.
// Tile: 32 batches x 32 gate rows per wg. K chunked by 128 through LDS, row-major
// padded layout, k-axis dot-product inner loop, K split across the 4 waves,
// register-prefetch double buffering (1 barrier/chunk), vectorized LDS reduce.
__global__ __launch_bounds__(256) void lstm_step(
    const float* __restrict__ x,
    const float* __restrict__ Wih0, const float* __restrict__ Whh0,
    const float* __restrict__ bih0, const float* __restrict__ bhh0,
    const float* __restrict__ Wih1, const float* __restrict__ Whh1,
    const float* __restrict__ bih1, const float* __restrict__ bhh1,
    float* __restrict__ ws, int s)
{
    // [A0 | W0 | A1 | W1], each 32 rows x LDSTR floats. 67584 B -> 2 blocks/CU.
    __shared__ float lds[4 * 32 * LDSTR];

    float* h0buf = ws;                 // [2][B*H]
    float* h1buf = ws + 2 * B_ * H_;   // [2][B*H]
    float* c0 = ws + 4 * B_ * H_;
    float* c1 = ws + 5 * B_ * H_;

    const int w = blockIdx.x;
    const int layer = w >> 8;
    const int r = w & 255;
    const int bb = r >> 5;   // batch block (8 of 32)
    const int hb = r & 31;   // h block (32 of 8 h-indices -> 32 gate rows)

    if (layer == 0 && s >= T_) return;
    if (layer == 1 && s < 1) return;
    const int t = (layer == 0) ? s : (s - 1);

    const float* hprev; const float* h0cur = nullptr;
    float* hout; float* cbuf;
    const float* Wih; const float* Whh; const float* bi; const float* bh;
    int nchunks;
    if (layer == 0) {
        hprev = h0buf + ((t - 1) & 1) * B_ * H_;
        hout  = h0buf + (t & 1) * B_ * H_;
        cbuf = c0; Wih = Wih0; Whh = Whh0; bi = bih0; bh = bhh0;
        nchunks = 3;   // K = 128 (x) + 256 (h0prev)
    } else {
        h0cur = h0buf + (t & 1) * B_ * H_;
        hprev = h1buf + ((t - 1) & 1) * B_ * H_;
        hout  = h1buf + (t & 1) * B_ * H_;
        cbuf = c1; Wih = Wih1; Whh = Whh1; bi = bih1; bh = bhh1;
        nchunks = 4;   // K = 256 (h0cur) + 256 (h1prev)
    }

    const int tid = threadIdx.x;
    const int srow = tid >> 3;   // staging row 0..31
    const int kv = tid & 7;      // staging k-vector lane
    const int wave = tid >> 6;
    const int lane = tid & 63;
    const int br = lane >> 3;    // batch sub-index 0..7 (lane's batches: br+8i)
    const int gc8 = lane & 7;    // h sub-index 0..7  (lane's gate rows: gc8+8g)
    // staging: local W row srow holds global gate row (srow/8)*H + hb*8 + srow%8
    // compute reads local row (8g + gc8) -> gate g, h-index gc8: consistent.
    const int grow = (srow >> 3) * H_ + hb * 8 + (srow & 7);

    auto a_src = [&](int cc) -> const float* {
        if (layer == 0) {
            if (cc == 0) return x + ((size_t)(bb * 32 + srow) * T_ + t) * I_;
            return hprev + (bb * 32 + srow) * H_ + (cc - 1) * 128;
        }
        if (cc < 2) return h0cur + (bb * 32 + srow) * H_ + cc * 128;
        return hprev + (bb * 32 + srow) * H_ + (cc - 2) * 128;
    };
    auto w_src = [&](int cc) -> const float* {
        if (layer == 0) {
            if (cc == 0) return Wih + grow * I_;
            return Whh + grow * H_ + (cc - 1) * 128;
        }
        if (cc < 2) return Wih + grow * H_ + cc * 128;
        return Whh + grow * H_ + (cc - 2) * 128;
    };

    float acc[4][4];
#pragma unroll
    for (int a = 0; a < 4; ++a)
#pragma unroll
        for (int b = 0; b < 4; ++b) acc[a][b] = 0.0f;

    float4 ra[4], rw[4];

    // prologue: stage chunk 0 into buffer 0
    {
        const float* ap = a_src(0);
        const float* wp = w_src(0);
#pragma unroll
        for (int m = 0; m < 4; ++m) {
            ra[m] = *(const float4*)(ap + (kv + 8 * m) * 4);
            rw[m] = *(const float4*)(wp + (kv + 8 * m) * 4);
        }
        float* ad = lds + srow * LDSTR;
        float* wd = lds + 32 * LDSTR + srow * LDSTR;
#pragma unroll
        for (int m = 0; m < 4; ++m) {
            *(float4*)(ad + (kv + 8 * m) * 4) = ra[m];
            *(float4*)(wd + (kv + 8 * m) * 4) = rw[m];
        }
    }
    __syncthreads();

    for (int cc = 0; cc < nchunks; ++cc) {
        const int d = cc & 1;
        const bool pf = (cc + 1 < nchunks);
        if (pf) {   // issue next-chunk global loads early (latency hides under FMA)
            const float* ap = a_src(cc + 1);
            const float* wp = w_src(cc + 1);
#pragma unroll
            for (int m = 0; m < 4; ++m) {
                ra[m] = *(const float4*)(ap + (kv + 8 * m) * 4);
                rw[m] = *(const float4*)(wp + (kv + 8 * m) * 4);
            }
        }
        const float* Ab = lds + (d * 2) * 32 * LDSTR;
        const float* Wb = lds + (d * 2 + 1) * 32 * LDSTR;
#pragma unroll
        for (int kk = 0; kk < 8; ++kk) {
            const int co = (wave * 8 + kk) * 4;   // this wave's k window
            float4 a0 = *(const float4*)(Ab + (br +  0) * LDSTR + co);
            float4 a1 = *(const float4*)(Ab + (br +  8) * LDSTR + co);
            float4 a2 = *(const float4*)(Ab + (br + 16) * LDSTR + co);
            float4 a3 = *(const float4*)(Ab + (br + 24) * LDSTR + co);
            float4 w0 = *(const float4*)(Wb + (gc8 +  0) * LDSTR + co);
            float4 w1 = *(const float4*)(Wb + (gc8 +  8) * LDSTR + co);
            float4 w2 = *(const float4*)(Wb + (gc8 + 16) * LDSTR + co);
            float4 w3 = *(const float4*)(Wb + (gc8 + 24) * LDSTR + co);
#define DOT4(ACC, A, W) ACC += A.x * W.x; ACC += A.y * W.y; ACC += A.z * W.z; ACC += A.w * W.w;
            DOT4(acc[0][0], a0, w0) DOT4(acc[0][1], a0, w1) DOT4(acc[0][2], a0, w2) DOT4(acc[0][3], a0, w3)
            DOT4(acc[1][0], a1, w0) DOT4(acc[1][1], a1, w1) DOT4(acc[1][2], a1, w2) DOT4(acc[1][3], a1, w3)
            DOT4(acc[2][0], a2, w0) DOT4(acc[2][1], a2, w1) DOT4(acc[2][2], a2, w2) DOT4(acc[2][3], a2, w3)
            DOT4(acc[3][0], a3, w0) DOT4(acc[3][1], a3, w1) DOT4(acc[3][2], a3, w2) DOT4(acc[3][3], a3, w3)
#undef DOT4
        }
        if (pf) {   // write prefetched chunk into the other buffer
            float* ad = lds + ((d ^ 1) * 2) * 32 * LDSTR + srow * LDSTR;
            float* wd = lds + ((d ^ 1) * 2 + 1) * 32 * LDSTR + srow * LDSTR;
#pragma unroll
            for (int m = 0; m < 4; ++m) {
                *(float4*)(ad + (kv + 8 * m) * 4) = ra[m];
                *(float4*)(wd + (kv + 8 * m) * 4) = rw[m];
            }
        }
        __syncthreads();
    }

    // cross-wave reduction (K-split): vectorized, padded stride (reuses buf0 area)
    float* red = lds;
    {
        const int base = (wave * 64 + lane) * RSTR;
#pragma unroll
        for (int i = 0; i < 4; ++i)
            *(float4*)(red + base + i * 4) =
                make_float4(acc[i][0], acc[i][1], acc[i][2], acc[i][3]);
    }
    __syncthreads();
    {
        const int lp = tid & 63;   // lane position within a wave
        const int iw = tid >> 6;   // which acc-row block this thread finalizes
        float4 v = *(const float4*)(red + lp * RSTR + iw * 4);
#pragma unroll
        for (int wv = 1; wv < 4; ++wv) {
            float4 u = *(const float4*)(red + (wv * 64 + lp) * RSTR + iw * 4);
            v.x += u.x; v.y += u.y; v.z += u.z; v.w += u.w;
        }
        const int hidx = hb * 8 + (lp & 7);
        const float gi = v.x + (bi[hidx] + bh[hidx]);
        const float gf = v.y + (bi[H_ + hidx] + bh[H_ + hidx]);
        const float gg = v.z + (bi[2 * H_ + hidx] + bh[2 * H_ + hidx]);
        const float go = v.w + (bi[3 * H_ + hidx] + bh[3 * H_ + hidx]);
        const float ig = fsig(gi);
        const float fg = fsig(gf);
        const float gn = ftanh(gg);
        const float og = fsig(go);
        const int b = bb * 32 + iw * 8 + (lp >> 3);
        const int ci = b * H_ + hidx;
        const float cn = fg * cbuf[ci] + ig * gn;
        cbuf[ci] = cn;
        hout[ci] = og * ftanh(cn);
    }
}

// out[b][c] = h1_final[b,:] . fcW[c,:] + fcb[c]; tiles [32 b x 32 c]
__global__ __launch_bounds__(256) void fc_kernel(
    const float* __restrict__ ws, const float* __restrict__ fcW,
    const float* __restrict__ fcb, float* __restrict__ out)
{
    __shared__ float As[128 * 36];
    __shared__ float Wsh[128 * 36];

    const float* h1 = ws + 3 * B_ * H_;  // h1buf[(T-1)&1] = h1buf[1]
    const int bb = blockIdx.x >> 5;
    const int cb = blockIdx.x & 31;
    const int tid = threadIdx.x;
    const int srow = tid >> 3;
    const int kv = tid & 7;
    const int wave = tid >> 6;
    const int lane = tid & 63;
    const int br = lane >> 3;
    const int gc8 = lane & 7;
    const int crow = cb * 32 + srow;

    float acc[4][4];
#pragma unroll
    for (int a = 0; a < 4; ++a)
#pragma unroll
        for (int b = 0; b < 4; ++b) acc[a][b] = 0.0f;

    for (int cc = 0; cc < 2; ++cc) {
        const float* ap = h1 + (bb * 32 + srow) * H_ + cc * 128;
#pragma unroll
        for (int i = 0; i < 4; ++i) {
            const int k4 = (kv + 8 * i) * 4;
            float4 va = *(const float4*)(ap + k4);
            As[(k4 + 0) * 36 + srow] = va.x;
            As[(k4 + 1) * 36 + srow] = va.y;
            As[(k4 + 2) * 36 + srow] = va.z;
            As[(k4 + 3) * 36 + srow] = va.w;
            float4 vw = make_float4(0.f, 0.f, 0.f, 0.f);
            if (crow < C_) vw = *(const float4*)(fcW + crow * H_ + cc * 128 + k4);
            Wsh[(k4 + 0) * 36 + srow] = vw.x;
            Wsh[(k4 + 1) * 36 + srow] = vw.y;
            Wsh[(k4 + 2) * 36 + srow] = vw.z;
            Wsh[(k4 + 3) * 36 + srow] = vw.w;
        }
        __syncthreads();
        const float* Ap = &As[(wave * 32) * 36 + br * 4];
        const float* Wp = &Wsh[(wave * 32) * 36 + gc8 * 4];
#pragma unroll
        for (int kk = 0; kk < 32; ++kk) {
            float4 a = *(const float4*)(Ap + kk * 36);
            float4 wv = *(const float4*)(Wp + kk * 36);
            acc[0][0] += a.x * wv.x; acc[0][1] += a.x * wv.y; acc[0][2] += a.x * wv.z; acc[0][3] += a.x * wv.w;
            acc[1][0] += a.y * wv.x; acc[1][1] += a.y * wv.y; acc[1][2] += a.y * wv.z; acc[1][3] += a.y * wv.w;
            acc[2][0] += a.z * wv.x; acc[2][1] += a.z * wv.y; acc[2][2] += a.z * wv.z; acc[2][3] += a.z * wv.w;
            acc[3][0] += a.w * wv.x; acc[3][1] += a.w * wv.y; acc[3][2] += a.w * wv.z; acc[3][3] += a.w * wv.w;
        }
        __syncthreads();
    }

    float* red = As;
    {
        const int base = tid * 16;
#pragma unroll
        for (int a = 0; a < 4; ++a)
#pragma unroll
            for (int b = 0; b < 4; ++b)
                red[base + a * 4 + b] = acc[a][b];
    }
    __syncthreads();
    {
        const int bl = tid >> 3;
        const int j = tid & 7;
#pragma unroll
        for (int g = 0; g < 4; ++g) {
            const int gc = g * 8 + j;
            const int br2 = bl >> 2, bi2 = bl & 3, gq = gc >> 2, gj = gc & 3;
            float v = 0.0f;
#pragma unroll
            for (int wv = 0; wv < 4; ++wv)
                v += red[(wv * 64 + br2 * 8 + gq) * 16 + bi2 * 4 + gj];
            const int cglob = cb * 32 + gc;
            if (cglob < C_) {
                v += fcb[cglob];
                out[(size_t)(bb * 32 + bl) * C_ + cglob] = v;
            }
        }
    }
}

extern "C" void kernel_launch(void* const* d_in, const int* in_sizes, int n_in,
                              void* d_out, int out_size, void* d_ws, size_t ws_size,
                              hipStream_t stream)
{
    const float* x    = (const float*)d_in[0];
    const float* Wih0 = (const float*)d_in[1];
    const float* Whh0 = (const float*)d_in[2];
    const float* bih0 = (const float*)d_in[3];
    const float* bhh0 = (const float*)d_in[4];
    const float* Wih1 = (const float*)d_in[5];
    const float* Whh1 = (const float*)d_in[6];
    const float* bih1 = (const float*)d_in[7];
    const float* bhh1 = (const float*)d_in[8];
    const float* fcW  = (const float*)d_in[9];
    const float* fcb  = (const float*)d_in[10];
    float* ws  = (float*)d_ws;
    float* out = (float*)d_out;

    // zero h0[2], h1[2], c0, c1 (ws is re-poisoned before every call)
    hipMemsetAsync(d_ws, 0, (size_t)6 * B_ * H_ * sizeof(float), stream);

    // pipelined: launch s does L0 @ t=s and L1 @ t=s-1 (independent within launch)
    for (int s = 0; s <= T_; ++s) {
        lstm_step<<<512, 256, 0, stream>>>(x, Wih0, Whh0, bih0, bhh0,
                                           Wih1, Whh1, bih1, bhh1, ws, s);
    }
    fc_kernel<<<256, 256, 0, stream>>>(ws, fcW, fcb, out);
}